// Round 3
// baseline (6745.125 us; speedup 1.0000x reference)
//
#include <hip/hip_runtime.h>
#include <math.h>

#define BATCH 8
#define SSIZE 1048576   // 128*128*64
#define KT 16

// ---------------- zero kernel (graph-capture-safe G clear) ----------------
__global__ void zero_kernel(float* __restrict__ p, int n) {
    int i = blockIdx.x * blockDim.x + threadIdx.x;
    if (i < n) p[i] = 0.0f;
}

// =====================================================================
// gram128: full G[b] (128x128) per block, split-K over grid.y.
// 512 threads; per-thread 8x4 complex acc (64 VGPRs). A-tile == B-tile.
// u(b,i,k) planar: off = b*SSIZE + i*SI + (k>>KL2)*SKH + (k&msk)
// =====================================================================
template<int SI_, int KL2_, int SKH_>
__global__ __launch_bounds__(512, 4)
void gram128_kernel(const float* __restrict__ srcR, const float* __restrict__ srcI,
                    float* __restrict__ G, int kPerBlock)
{
    const int b      = blockIdx.x;
    const int kbase0 = blockIdx.y * kPerBlock;
    const int t  = threadIdx.x;
    const int ti = t & 15;        // 16 row-groups (8 rows each)
    const int tj = t >> 4;        // 32 col-groups (4 cols each)

    __shared__ float2 As[2][16][130];   // [buf][kk][row]; row=1040B, 16B-aligned

    float accr[8][4] = {{0.f}}, acci[8][4] = {{0.f}};

    const size_t boff = (size_t)b * SSIZE;
    const int nT = kPerBlock >> 4;

    // staging: thread -> (row r0, k-quad kq); one float4 per plane per tile
    const int kq = t & 3;
    const int r0 = t >> 2;        // [0,128)

    float4 pR, pI;

    #define GADDR(ii, k) (boff + (size_t)(ii) * SI_ + \
        (size_t)((k) >> KL2_) * SKH_ + (size_t)((k) & ((1 << KL2_) - 1)))

    {   // prologue: tile 0
        const size_t off = GADDR(r0, kbase0 + kq * 4);
        pR = *(const float4*)(srcR + off);
        pI = *(const float4*)(srcI + off);
        As[0][kq * 4 + 0][r0] = make_float2(pR.x, pI.x);
        As[0][kq * 4 + 1][r0] = make_float2(pR.y, pI.y);
        As[0][kq * 4 + 2][r0] = make_float2(pR.z, pI.z);
        As[0][kq * 4 + 3][r0] = make_float2(pR.w, pI.w);
    }
    __syncthreads();

    for (int kt = 0; kt < nT; kt++) {
        const int cur = kt & 1, nxt = cur ^ 1;
        const bool have_next = (kt + 1 < nT);
        if (have_next) {
            const size_t off = GADDR(r0, kbase0 + (kt + 1) * KT + kq * 4);
            pR = *(const float4*)(srcR + off);
            pI = *(const float4*)(srcI + off);
        }
        #pragma unroll
        for (int kk = 0; kk < KT; kk++) {
            float4 a4[4], b4[2];
            #pragma unroll
            for (int q = 0; q < 4; q++) a4[q] = *(const float4*)&As[cur][kk][2 * ti + 32 * q];
            #pragma unroll
            for (int q = 0; q < 2; q++) b4[q] = *(const float4*)&As[cur][kk][2 * tj + 64 * q];
            #pragma unroll
            for (int r = 0; r < 8; r++) {
                const float ax = (r & 1) ? a4[r >> 1].z : a4[r >> 1].x;
                const float ay = (r & 1) ? a4[r >> 1].w : a4[r >> 1].y;
                #pragma unroll
                for (int c = 0; c < 4; c++) {
                    const float bx = (c & 1) ? b4[c >> 1].z : b4[c >> 1].x;
                    const float by = (c & 1) ? b4[c >> 1].w : b4[c >> 1].y;
                    accr[r][c] = fmaf(ax,  bx, accr[r][c]);
                    accr[r][c] = fmaf(-ay, by, accr[r][c]);
                    acci[r][c] = fmaf(ax,  by, acci[r][c]);
                    acci[r][c] = fmaf(ay,  bx, acci[r][c]);
                }
            }
        }
        if (have_next) {
            As[nxt][kq * 4 + 0][r0] = make_float2(pR.x, pI.x);
            As[nxt][kq * 4 + 1][r0] = make_float2(pR.y, pI.y);
            As[nxt][kq * 4 + 2][r0] = make_float2(pR.z, pI.z);
            As[nxt][kq * 4 + 3][r0] = make_float2(pR.w, pI.w);
        }
        __syncthreads();
    }
    #undef GADDR

    float* Gb = G + (size_t)b * 128 * 128 * 2;
    #pragma unroll
    for (int r = 0; r < 8; r++) {
        const int i = 2 * ti + (r & 1) + 32 * (r >> 1);
        #pragma unroll
        for (int c = 0; c < 4; c++) {
            const int j = 2 * tj + (c & 1) + 64 * (c >> 1);
            atomicAdd(&Gb[(i * 128 + j) * 2 + 0], accr[r][c]);
            atomicAdd(&Gb[(i * 128 + j) * 2 + 1], acci[r][c]);
        }
    }
}

// =====================================================================
// gram64: mode 2 (d=64). SI=1 (i contiguous), k: (k&127)*64 + (k>>7)*8192.
// (unchanged from round 2 — no spills, float4 staged, dbuf)
// =====================================================================
__global__ __launch_bounds__(256, 2)
void gram64_kernel(const float* __restrict__ srcR, const float* __restrict__ srcI,
                   float* __restrict__ G, int kPerBlock)
{
    const int b      = blockIdx.x;
    const int kbase0 = blockIdx.y * kPerBlock;
    const int t  = threadIdx.x;
    const int ti = t & 15, tj = t >> 4;

    __shared__ float2 As[2][32][66];

    float accr[4][4] = {{0.f}}, acci[4][4] = {{0.f}};

    const size_t boff = (size_t)b * SSIZE;
    const int nT = kPerBlock >> 5;

    const int ii4 = (t & 15) * 4;
    const int kk0 = t >> 4;

    float4 pR[2], pI[2];

    #define GADDR64(ii, k) (boff + (size_t)(ii) + \
        (size_t)((k) & 127) * 64 + (size_t)((k) >> 7) * 8192)

    {
        const int kb = kbase0;
        #pragma unroll
        for (int m = 0; m < 2; m++) {
            const int kk = kk0 + 16 * m;
            const size_t off = GADDR64(ii4, kb + kk);
            pR[m] = *(const float4*)(srcR + off);
            pI[m] = *(const float4*)(srcI + off);
        }
        #pragma unroll
        for (int m = 0; m < 2; m++) {
            const int kk = kk0 + 16 * m;
            *(float4*)&As[0][kk][ii4]     = make_float4(pR[m].x, pI[m].x, pR[m].y, pI[m].y);
            *(float4*)&As[0][kk][ii4 + 2] = make_float4(pR[m].z, pI[m].z, pR[m].w, pI[m].w);
        }
    }
    __syncthreads();

    for (int kt = 0; kt < nT; kt++) {
        const int cur = kt & 1, nxt = cur ^ 1;
        const bool have_next = (kt + 1 < nT);
        if (have_next) {
            const int kb = kbase0 + (kt + 1) * 32;
            #pragma unroll
            for (int m = 0; m < 2; m++) {
                const int kk = kk0 + 16 * m;
                const size_t off = GADDR64(ii4, kb + kk);
                pR[m] = *(const float4*)(srcR + off);
                pI[m] = *(const float4*)(srcI + off);
            }
        }
        #pragma unroll
        for (int kk = 0; kk < 32; kk++) {
            float4 a4[2], b4[2];
            #pragma unroll
            for (int r = 0; r < 2; r++) a4[r] = *(const float4*)&As[cur][kk][ti * 2 + 32 * r];
            #pragma unroll
            for (int c = 0; c < 2; c++) b4[c] = *(const float4*)&As[cur][kk][tj * 2 + 32 * c];
            #pragma unroll
            for (int r = 0; r < 4; r++) {
                const float ax = (r & 1) ? a4[r >> 1].z : a4[r >> 1].x;
                const float ay = (r & 1) ? a4[r >> 1].w : a4[r >> 1].y;
                #pragma unroll
                for (int c = 0; c < 4; c++) {
                    const float bx = (c & 1) ? b4[c >> 1].z : b4[c >> 1].x;
                    const float by = (c & 1) ? b4[c >> 1].w : b4[c >> 1].y;
                    accr[r][c] = fmaf(ax,  bx, accr[r][c]);
                    accr[r][c] = fmaf(-ay, by, accr[r][c]);
                    acci[r][c] = fmaf(ax,  by, acci[r][c]);
                    acci[r][c] = fmaf(ay,  bx, acci[r][c]);
                }
            }
        }
        if (have_next) {
            #pragma unroll
            for (int m = 0; m < 2; m++) {
                const int kk = kk0 + 16 * m;
                *(float4*)&As[nxt][kk][ii4]     = make_float4(pR[m].x, pI[m].x, pR[m].y, pI[m].y);
                *(float4*)&As[nxt][kk][ii4 + 2] = make_float4(pR[m].z, pI[m].z, pR[m].w, pI[m].w);
            }
        }
        __syncthreads();
    }
    #undef GADDR64

    float* Gb = G + (size_t)b * 64 * 64 * 2;
    #pragma unroll
    for (int r = 0; r < 4; r++) {
        const int i = 2 * ti + (r & 1) + 32 * (r >> 1);
        #pragma unroll
        for (int c = 0; c < 4; c++) {
            const int j = 2 * tj + (c & 1) + 32 * (c >> 1);
            atomicAdd(&Gb[(i * 64 + j) * 2 + 0], accr[r][c]);
            atomicAdd(&Gb[(i * 64 + j) * 2 + 1], acci[r][c]);
        }
    }
}

// ---------------- score/softmax/phase -> routing matrix M ----------------
__global__ __launch_bounds__(128)
void score_kernel(const float* __restrict__ G,
                  const float* __restrict__ Wre, const float* __restrict__ Wim,
                  const float* __restrict__ log_tau,
                  float2* __restrict__ Mout, int d)
{
    const int b = blockIdx.y;
    const int i = blockIdx.x;
    const int j = threadIdx.x;

    const float2* Gb = (const float2*)G + (size_t)b * d * d;

    float sre = 0.f, sim = 0.f;
    for (int l = 0; l < d; l++) {
        float wr = Wre[i * d + l];
        float wi = Wim[i * d + l];
        float2 g = Gb[l * d + j];
        sre = fmaf(wr, g.x, sre);
        sre = fmaf(-wi, g.y, sre);
        sim = fmaf(wr, g.y, sim);
        sim = fmaf(wi, g.x, sim);
    }

    float mag = sqrtf(sre * sre + sim * sim);
    float tau = fmaxf(expf(log_tau[0]), 1e-8f);
    float scale = tau * sqrtf((float)SSIZE / (float)d);
    float mval = mag / scale;

    __shared__ float red[128];
    red[j] = mval;
    __syncthreads();
    for (int s = d >> 1; s > 0; s >>= 1) {
        if (j < s) red[j] = fmaxf(red[j], red[j + s]);
        __syncthreads();
    }
    float mx = red[0];
    __syncthreads();
    float e = expf(mval - mx);
    red[j] = e;
    __syncthreads();
    for (int s = d >> 1; s > 0; s >>= 1) {
        if (j < s) red[j] += red[j + s];
        __syncthreads();
    }
    float routing = e / red[0];

    float safe = fmaxf(mag, 1e-8f);
    float pre, pim;
    if (mag > 1e-8f) { pre = sre / safe; pim = sim / safe; }
    else             { pre = 1.f;       pim = 0.f; }

    Mout[(size_t)b * d * d + i * d + j] = make_float2(routing * pre, routing * pim);
}

// =====================================================================
// mix128: dst(b,i,k) = sum_j M[b,i,j]*u(b,j,k), d=128, for modes 0/1
// (SKL==1 within 2^KL2 chunks). Tile 64 i x 128 k; 256 thr; 4x8/thread.
// =====================================================================
template<int SI_, int KL2_, int SKH_>
__global__ __launch_bounds__(256, 3)
void mix128_kernel(const float* __restrict__ srcR, const float* __restrict__ srcI,
                   const float2* __restrict__ M,
                   float* __restrict__ dstR, float* __restrict__ dstI)
{
    const int kb0 = blockIdx.x << 7;   // 128-wide k tile
    const int it  = blockIdx.y << 6;   // 64-wide i tile
    const int b   = blockIdx.z;

    const int t  = threadIdx.x;
    const int ti = t & 15;   // 16 i-groups (4 rows each)
    const int tj = t >> 4;   // 16 k-groups (8 cols each)

    __shared__ float2 Ms[2][16][66];    // [buf][jj][ii]
    __shared__ float2 Us[2][16][130];   // [buf][jj][kk]

    float accr[4][8] = {{0.f}}, acci[4][8] = {{0.f}};

    const size_t boff = (size_t)b * SSIZE;
    const float2* Mb  = M + (size_t)b * 128 * 128;

    #define GADDR(jj, k) (boff + (size_t)(jj) * SI_ + \
        (size_t)((k) >> KL2_) * SKH_ + (size_t)((k) & ((1 << KL2_) - 1)))

    // staging maps
    const int mrow = t >> 2;        // [0,64) i for M
    const int mjq  = t & 3;         // jj quad
    const int ujj  = t >> 4;        // [0,16) j row for U
    const int ukq  = t & 15;        // k float4 index within half-tile

    float4 mA, mB;                  // 4 complex of M
    float4 uRa, uIa, uRb, uIb;      // 2x float4 per plane of U

    {   // prologue: jb = 0
        const float2* mp = &Mb[(size_t)(it + mrow) * 128 + mjq * 4];
        mA = *(const float4*)mp;
        mB = *(const float4*)(mp + 2);
        const size_t offA = GADDR(ujj, kb0 + ukq * 4);
        const size_t offB = GADDR(ujj, kb0 + 64 + ukq * 4);
        uRa = *(const float4*)(srcR + offA);
        uIa = *(const float4*)(srcI + offA);
        uRb = *(const float4*)(srcR + offB);
        uIb = *(const float4*)(srcI + offB);
        Ms[0][mjq * 4 + 0][mrow] = make_float2(mA.x, mA.y);
        Ms[0][mjq * 4 + 1][mrow] = make_float2(mA.z, mA.w);
        Ms[0][mjq * 4 + 2][mrow] = make_float2(mB.x, mB.y);
        Ms[0][mjq * 4 + 3][mrow] = make_float2(mB.z, mB.w);
        *(float4*)&Us[0][ujj][ukq * 4]      = make_float4(uRa.x, uIa.x, uRa.y, uIa.y);
        *(float4*)&Us[0][ujj][ukq * 4 + 2]  = make_float4(uRa.z, uIa.z, uRa.w, uIa.w);
        *(float4*)&Us[0][ujj][64 + ukq * 4]     = make_float4(uRb.x, uIb.x, uRb.y, uIb.y);
        *(float4*)&Us[0][ujj][64 + ukq * 4 + 2] = make_float4(uRb.z, uIb.z, uRb.w, uIb.w);
    }
    __syncthreads();

    for (int jt = 0; jt < 8; jt++) {
        const int cur = jt & 1, nxt = cur ^ 1;
        const bool have_next = (jt + 1 < 8);
        if (have_next) {
            const int jb = (jt + 1) * 16;
            const float2* mp = &Mb[(size_t)(it + mrow) * 128 + jb + mjq * 4];
            mA = *(const float4*)mp;
            mB = *(const float4*)(mp + 2);
            const size_t offA = GADDR(jb + ujj, kb0 + ukq * 4);
            const size_t offB = GADDR(jb + ujj, kb0 + 64 + ukq * 4);
            uRa = *(const float4*)(srcR + offA);
            uIa = *(const float4*)(srcI + offA);
            uRb = *(const float4*)(srcR + offB);
            uIb = *(const float4*)(srcI + offB);
        }
        #pragma unroll
        for (int kk = 0; kk < KT; kk++) {
            float4 m4[2], u4[4];
            #pragma unroll
            for (int q = 0; q < 2; q++) m4[q] = *(const float4*)&Ms[cur][kk][2 * ti + 32 * q];
            #pragma unroll
            for (int q = 0; q < 4; q++) u4[q] = *(const float4*)&Us[cur][kk][2 * tj + 32 * q];
            #pragma unroll
            for (int r = 0; r < 4; r++) {
                const float mx = (r & 1) ? m4[r >> 1].z : m4[r >> 1].x;
                const float my = (r & 1) ? m4[r >> 1].w : m4[r >> 1].y;
                #pragma unroll
                for (int c = 0; c < 8; c++) {
                    const float ux = (c & 1) ? u4[c >> 1].z : u4[c >> 1].x;
                    const float uy = (c & 1) ? u4[c >> 1].w : u4[c >> 1].y;
                    accr[r][c] = fmaf(mx,  ux, accr[r][c]);
                    accr[r][c] = fmaf(-my, uy, accr[r][c]);
                    acci[r][c] = fmaf(mx,  uy, acci[r][c]);
                    acci[r][c] = fmaf(my,  ux, acci[r][c]);
                }
            }
        }
        if (have_next) {
            Ms[nxt][mjq * 4 + 0][mrow] = make_float2(mA.x, mA.y);
            Ms[nxt][mjq * 4 + 1][mrow] = make_float2(mA.z, mA.w);
            Ms[nxt][mjq * 4 + 2][mrow] = make_float2(mB.x, mB.y);
            Ms[nxt][mjq * 4 + 3][mrow] = make_float2(mB.z, mB.w);
            *(float4*)&Us[nxt][ujj][ukq * 4]      = make_float4(uRa.x, uIa.x, uRa.y, uIa.y);
            *(float4*)&Us[nxt][ujj][ukq * 4 + 2]  = make_float4(uRa.z, uIa.z, uRa.w, uIa.w);
            *(float4*)&Us[nxt][ujj][64 + ukq * 4]     = make_float4(uRb.x, uIb.x, uRb.y, uIb.y);
            *(float4*)&Us[nxt][ujj][64 + ukq * 4 + 2] = make_float4(uRb.z, uIb.z, uRb.w, uIb.w);
        }
        __syncthreads();
    }

    // epilogue: float2 stores per (row, k-pair)
    #pragma unroll
    for (int r = 0; r < 4; r++) {
        const int i = it + 2 * ti + (r & 1) + 32 * (r >> 1);
        #pragma unroll
        for (int p = 0; p < 4; p++) {
            const int k = kb0 + 2 * tj + 32 * p;
            const size_t off = GADDR(i, k) - (size_t)(2 * tj + 32 * p) * SI_
                             + (size_t)i * SI_ - (size_t)i * SI_;  // (kept simple below)
            const size_t o2 = boff + (size_t)i * SI_ +
                (size_t)(k >> KL2_) * SKH_ + (size_t)(k & ((1 << KL2_) - 1));
            *(float2*)(dstR + o2) = make_float2(accr[r][2 * p], accr[r][2 * p + 1]);
            *(float2*)(dstI + o2) = make_float2(acci[r][2 * p], acci[r][2 * p + 1]);
            (void)off;
        }
    }
    #undef GADDR
}

// ---------------- generic mix (used for mode 2) ----------------
__global__ __launch_bounds__(256)
void mix_kernel(const float* __restrict__ srcR, const float* __restrict__ srcI,
                const float2* __restrict__ M,
                float* __restrict__ dstR, float* __restrict__ dstI,
                int d, int SI, int KL2, int SKL, int SKH)
{
    const int kb0 = blockIdx.x << 6;
    const int it  = blockIdx.y << 6;
    const int b   = blockIdx.z;
    const int msk = (1 << KL2) - 1;

    __shared__ float2 Ms[KT][66];
    __shared__ float2 Us[KT][66];

    const int t  = threadIdx.x;
    const int ti = t & 15, tj = t >> 4;

    float accr[4][4] = {{0}}, acci[4][4] = {{0}};

    const size_t boff = (size_t)b * SSIZE;
    const float2* Mb  = M + (size_t)b * d * d;
    const size_t koff = (size_t)(kb0 >> KL2) * SKH + (size_t)(kb0 & msk) * SKL;

    for (int jb = 0; jb < d; jb += KT) {
        #pragma unroll
        for (int iter = 0; iter < 4; iter++) {
            int l  = iter * 256 + t;
            int jj = l & 15;
            int ii = l >> 4;
            Ms[jj][ii] = Mb[(size_t)(it + ii) * d + (jb + jj)];
        }
        #pragma unroll
        for (int iter = 0; iter < 4; iter++) {
            int l  = iter * 256 + t;
            int kk = l & 63;
            int jj = l >> 6;
            size_t off = boff + (size_t)(jb + jj) * SI + koff + (size_t)kk * SKL;
            Us[jj][kk] = make_float2(srcR[off], srcI[off]);
        }
        __syncthreads();
        #pragma unroll
        for (int jj = 0; jj < KT; jj++) {
            float2 m[4], u[4];
            #pragma unroll
            for (int r = 0; r < 4; r++) m[r] = Ms[jj][ti * 4 + r];
            #pragma unroll
            for (int c = 0; c < 4; c++) u[c] = Us[jj][tj * 4 + c];
            #pragma unroll
            for (int r = 0; r < 4; r++)
                #pragma unroll
                for (int c = 0; c < 4; c++) {
                    accr[r][c] = fmaf(m[r].x,  u[c].x, accr[r][c]);
                    accr[r][c] = fmaf(-m[r].y, u[c].y, accr[r][c]);
                    acci[r][c] = fmaf(m[r].x,  u[c].y, acci[r][c]);
                    acci[r][c] = fmaf(m[r].y,  u[c].x, acci[r][c]);
                }
        }
        __syncthreads();
    }

    #pragma unroll
    for (int r = 0; r < 4; r++)
        #pragma unroll
        for (int c = 0; c < 4; c++) {
            int i = it + ti * 4 + r;
            int kc = tj * 4 + c;
            size_t pos = boff + (size_t)i * SI + koff + (size_t)kc * SKL;
            dstR[pos] = accr[r][c];
            dstI[pos] = acci[r][c];
        }
}

extern "C" void kernel_launch(void* const* d_in, const int* in_sizes, int n_in,
                              void* d_out, int out_size, void* d_ws, size_t ws_size,
                              hipStream_t stream)
{
    const float* xr  = (const float*)d_in[0];
    const float* xi  = (const float*)d_in[1];
    const float* w0r = (const float*)d_in[2];
    const float* w0i = (const float*)d_in[3];
    const float* w1r = (const float*)d_in[4];
    const float* w1i = (const float*)d_in[5];
    const float* w2r = (const float*)d_in[6];
    const float* w2i = (const float*)d_in[7];
    const float* lt  = (const float*)d_in[8];

    float* outR = (float*)d_out;
    float* outI = outR + (size_t)BATCH * SSIZE;

    float*  wsR = (float*)d_ws;
    float*  wsI = wsR + (size_t)BATCH * SSIZE;
    float*  Gf  = wsI + (size_t)BATCH * SSIZE;
    float2* Mf  = (float2*)(Gf + (size_t)BATCH * 128 * 128 * 2);

    const int nG = BATCH * 128 * 128 * 2;

    // ---------------- mode 0: d=128, SI=8192, KL2=13
    zero_kernel<<<dim3((nG + 255) / 256), 256, 0, stream>>>(Gf, nG);
    gram128_kernel<8192, 13, 0><<<dim3(BATCH, 64), 512, 0, stream>>>(xr, xi, Gf, 128);
    score_kernel<<<dim3(128, BATCH), 128, 0, stream>>>(Gf, w0r, w0i, lt, Mf, 128);
    mix128_kernel<8192, 13, 0><<<dim3(64, 2, BATCH), 256, 0, stream>>>(xr, xi, Mf, outR, outI);

    // ---------------- mode 1: d=128, SI=64, KL2=6, SKH=8192
    zero_kernel<<<dim3((nG + 255) / 256), 256, 0, stream>>>(Gf, nG);
    gram128_kernel<64, 6, 8192><<<dim3(BATCH, 64), 512, 0, stream>>>(outR, outI, Gf, 128);
    score_kernel<<<dim3(128, BATCH), 128, 0, stream>>>(Gf, w1r, w1i, lt, Mf, 128);
    mix128_kernel<64, 6, 8192><<<dim3(64, 2, BATCH), 256, 0, stream>>>(outR, outI, Mf, wsR, wsI);

    // ---------------- mode 2: d=64, SI=1, k: (k&127)*64 + (k>>7)*8192
    zero_kernel<<<dim3((nG + 255) / 256), 256, 0, stream>>>(Gf, nG);
    gram64_kernel<<<dim3(BATCH, 64), 256, 0, stream>>>(wsR, wsI, Gf, 256);
    score_kernel<<<dim3(64, BATCH), 64, 0, stream>>>(Gf, w2r, w2i, lt, Mf, 64);
    mix_kernel<<<dim3(256, 1, BATCH), 256, 0, stream>>>(wsR, wsI, Mf, outR, outI,
                 64, 1, 7, 64, 8192);
}

// Round 4
// 1637.389 us; speedup vs baseline: 4.1194x; 4.1194x over previous
//
#include <hip/hip_runtime.h>
#include <math.h>

#define BATCH 8
#define SSIZE 1048576   // 128*128*64
#define KT 16

// ---------------- zero kernel (graph-capture-safe G clear) ----------------
__global__ void zero_kernel(float* __restrict__ p, int n) {
    int i = blockIdx.x * blockDim.x + threadIdx.x;
    if (i < n) p[i] = 0.0f;
}

// =====================================================================
// gram_v4 (modes 0/1, k-contiguous): 64x64 G-tile per block, 4x4 complex
// per thread (32 acc VGPRs -> no spill), single-buffer LDS, float4 global
// staging, conflict-free float4 fragment reads. Occupancy does the latency
// hiding (target 64 VGPR => 8 waves/SIMD).
// u(b,i,k): off = b*SSIZE + i*SI + (k>>KL2)*SKH + (k & ((1<<KL2)-1))
// =====================================================================
template<int SI_, int KL2_, int SKH_>
__global__ __launch_bounds__(256)
void gram_v4_kernel(const float* __restrict__ srcR, const float* __restrict__ srcI,
                    float* __restrict__ G, int kPerBlock)
{
    const int it = (blockIdx.x >> 1) << 6;   // 2x2 tiles of 64 (d=128)
    const int jt = (blockIdx.x & 1) << 6;
    const int b  = blockIdx.y;
    const int kbase0 = blockIdx.z * kPerBlock;

    const int t  = threadIdx.x;
    const int ti = t & 15, tj = t >> 4;

    __shared__ float2 As[KT][66];   // [kk][row]; row pitch 528B (16B-aligned)
    __shared__ float2 Bs[KT][66];

    float accr[4][4] = {{0.f}}, acci[4][4] = {{0.f}};

    const size_t boff = (size_t)b * SSIZE;
    const int nT = kPerBlock >> 4;

    // staging map: kq = float4 index in k (0..3), r0 = row (0..63)
    const int kq = t & 3;
    const int r0 = t >> 2;

    #define GADDR(ii, k) (boff + (size_t)(ii) * SI_ + \
        (size_t)((k) >> KL2_) * SKH_ + (size_t)((k) & ((1 << KL2_) - 1)))

    for (int kt = 0; kt < nT; kt++) {
        const int kb = kbase0 + kt * KT;
        const size_t offA = GADDR(it + r0, kb + kq * 4);
        const size_t offB = GADDR(jt + r0, kb + kq * 4);
        const float4 aR = *(const float4*)(srcR + offA);
        const float4 aI = *(const float4*)(srcI + offA);
        const float4 bR = *(const float4*)(srcR + offB);
        const float4 bI = *(const float4*)(srcI + offB);

        As[kq * 4 + 0][r0] = make_float2(aR.x, aI.x);
        As[kq * 4 + 1][r0] = make_float2(aR.y, aI.y);
        As[kq * 4 + 2][r0] = make_float2(aR.z, aI.z);
        As[kq * 4 + 3][r0] = make_float2(aR.w, aI.w);
        Bs[kq * 4 + 0][r0] = make_float2(bR.x, bI.x);
        Bs[kq * 4 + 1][r0] = make_float2(bR.y, bI.y);
        Bs[kq * 4 + 2][r0] = make_float2(bR.z, bI.z);
        Bs[kq * 4 + 3][r0] = make_float2(bR.w, bI.w);
        __syncthreads();

        #pragma unroll
        for (int kk = 0; kk < KT; kk++) {
            float4 a4[2], b4[2];
            #pragma unroll
            for (int q = 0; q < 2; q++) a4[q] = *(const float4*)&As[kk][2 * ti + 32 * q];
            #pragma unroll
            for (int q = 0; q < 2; q++) b4[q] = *(const float4*)&Bs[kk][2 * tj + 32 * q];
            #pragma unroll
            for (int r = 0; r < 4; r++) {
                const float ax = (r & 1) ? a4[r >> 1].z : a4[r >> 1].x;
                const float ay = (r & 1) ? a4[r >> 1].w : a4[r >> 1].y;
                #pragma unroll
                for (int c = 0; c < 4; c++) {
                    const float bx = (c & 1) ? b4[c >> 1].z : b4[c >> 1].x;
                    const float by = (c & 1) ? b4[c >> 1].w : b4[c >> 1].y;
                    accr[r][c] = fmaf(ax,  bx, accr[r][c]);
                    accr[r][c] = fmaf(-ay, by, accr[r][c]);
                    acci[r][c] = fmaf(ax,  by, acci[r][c]);
                    acci[r][c] = fmaf(ay,  bx, acci[r][c]);
                }
            }
        }
        __syncthreads();
    }
    #undef GADDR

    float* Gb = G + (size_t)b * 128 * 128 * 2;
    #pragma unroll
    for (int r = 0; r < 4; r++) {
        const int i = it + 2 * ti + (r & 1) + 32 * (r >> 1);
        #pragma unroll
        for (int c = 0; c < 4; c++) {
            const int j = jt + 2 * tj + (c & 1) + 32 * (c >> 1);
            atomicAdd(&Gb[(i * 128 + j) * 2 + 0], accr[r][c]);
            atomicAdd(&Gb[(i * 128 + j) * 2 + 1], acci[r][c]);
        }
    }
}

// =====================================================================
// gram64: mode 2 (d=64). SI=1 (i contiguous), k: (k&127)*64 + (k>>7)*8192.
// Known-good round-2 version (kept verbatim).
// =====================================================================
__global__ __launch_bounds__(256, 2)
void gram64_kernel(const float* __restrict__ srcR, const float* __restrict__ srcI,
                   float* __restrict__ G, int kPerBlock)
{
    const int b      = blockIdx.x;
    const int kbase0 = blockIdx.y * kPerBlock;
    const int t  = threadIdx.x;
    const int ti = t & 15, tj = t >> 4;

    __shared__ float2 As[2][32][66];

    float accr[4][4] = {{0.f}}, acci[4][4] = {{0.f}};

    const size_t boff = (size_t)b * SSIZE;
    const int nT = kPerBlock >> 5;

    const int ii4 = (t & 15) * 4;
    const int kk0 = t >> 4;

    float4 pR[2], pI[2];

    #define GADDR64(ii, k) (boff + (size_t)(ii) + \
        (size_t)((k) & 127) * 64 + (size_t)((k) >> 7) * 8192)

    {
        const int kb = kbase0;
        #pragma unroll
        for (int m = 0; m < 2; m++) {
            const int kk = kk0 + 16 * m;
            const size_t off = GADDR64(ii4, kb + kk);
            pR[m] = *(const float4*)(srcR + off);
            pI[m] = *(const float4*)(srcI + off);
        }
        #pragma unroll
        for (int m = 0; m < 2; m++) {
            const int kk = kk0 + 16 * m;
            *(float4*)&As[0][kk][ii4]     = make_float4(pR[m].x, pI[m].x, pR[m].y, pI[m].y);
            *(float4*)&As[0][kk][ii4 + 2] = make_float4(pR[m].z, pI[m].z, pR[m].w, pI[m].w);
        }
    }
    __syncthreads();

    for (int kt = 0; kt < nT; kt++) {
        const int cur = kt & 1, nxt = cur ^ 1;
        const bool have_next = (kt + 1 < nT);
        if (have_next) {
            const int kb = kbase0 + (kt + 1) * 32;
            #pragma unroll
            for (int m = 0; m < 2; m++) {
                const int kk = kk0 + 16 * m;
                const size_t off = GADDR64(ii4, kb + kk);
                pR[m] = *(const float4*)(srcR + off);
                pI[m] = *(const float4*)(srcI + off);
            }
        }
        #pragma unroll
        for (int kk = 0; kk < 32; kk++) {
            float4 a4[2], b4[2];
            #pragma unroll
            for (int r = 0; r < 2; r++) a4[r] = *(const float4*)&As[cur][kk][ti * 2 + 32 * r];
            #pragma unroll
            for (int c = 0; c < 2; c++) b4[c] = *(const float4*)&As[cur][kk][tj * 2 + 32 * c];
            #pragma unroll
            for (int r = 0; r < 4; r++) {
                const float ax = (r & 1) ? a4[r >> 1].z : a4[r >> 1].x;
                const float ay = (r & 1) ? a4[r >> 1].w : a4[r >> 1].y;
                #pragma unroll
                for (int c = 0; c < 4; c++) {
                    const float bx = (c & 1) ? b4[c >> 1].z : b4[c >> 1].x;
                    const float by = (c & 1) ? b4[c >> 1].w : b4[c >> 1].y;
                    accr[r][c] = fmaf(ax,  bx, accr[r][c]);
                    accr[r][c] = fmaf(-ay, by, accr[r][c]);
                    acci[r][c] = fmaf(ax,  by, acci[r][c]);
                    acci[r][c] = fmaf(ay,  bx, acci[r][c]);
                }
            }
        }
        if (have_next) {
            #pragma unroll
            for (int m = 0; m < 2; m++) {
                const int kk = kk0 + 16 * m;
                *(float4*)&As[nxt][kk][ii4]     = make_float4(pR[m].x, pI[m].x, pR[m].y, pI[m].y);
                *(float4*)&As[nxt][kk][ii4 + 2] = make_float4(pR[m].z, pI[m].z, pR[m].w, pI[m].w);
            }
        }
        __syncthreads();
    }
    #undef GADDR64

    float* Gb = G + (size_t)b * 64 * 64 * 2;
    #pragma unroll
    for (int r = 0; r < 4; r++) {
        const int i = 2 * ti + (r & 1) + 32 * (r >> 1);
        #pragma unroll
        for (int c = 0; c < 4; c++) {
            const int j = 2 * tj + (c & 1) + 32 * (c >> 1);
            atomicAdd(&Gb[(i * 64 + j) * 2 + 0], accr[r][c]);
            atomicAdd(&Gb[(i * 64 + j) * 2 + 1], acci[r][c]);
        }
    }
}

// ---------------- score/softmax/phase -> routing matrix M ----------------
__global__ __launch_bounds__(128)
void score_kernel(const float* __restrict__ G,
                  const float* __restrict__ Wre, const float* __restrict__ Wim,
                  const float* __restrict__ log_tau,
                  float2* __restrict__ Mout, int d)
{
    const int b = blockIdx.y;
    const int i = blockIdx.x;
    const int j = threadIdx.x;

    const float2* Gb = (const float2*)G + (size_t)b * d * d;

    float sre = 0.f, sim = 0.f;
    for (int l = 0; l < d; l++) {
        float wr = Wre[i * d + l];
        float wi = Wim[i * d + l];
        float2 g = Gb[l * d + j];
        sre = fmaf(wr, g.x, sre);
        sre = fmaf(-wi, g.y, sre);
        sim = fmaf(wr, g.y, sim);
        sim = fmaf(wi, g.x, sim);
    }

    float mag = sqrtf(sre * sre + sim * sim);
    float tau = fmaxf(expf(log_tau[0]), 1e-8f);
    float scale = tau * sqrtf((float)SSIZE / (float)d);
    float mval = mag / scale;

    __shared__ float red[128];
    red[j] = mval;
    __syncthreads();
    for (int s = d >> 1; s > 0; s >>= 1) {
        if (j < s) red[j] = fmaxf(red[j], red[j + s]);
        __syncthreads();
    }
    float mx = red[0];
    __syncthreads();
    float e = expf(mval - mx);
    red[j] = e;
    __syncthreads();
    for (int s = d >> 1; s > 0; s >>= 1) {
        if (j < s) red[j] += red[j + s];
        __syncthreads();
    }
    float routing = e / red[0];

    float safe = fmaxf(mag, 1e-8f);
    float pre, pim;
    if (mag > 1e-8f) { pre = sre / safe; pim = sim / safe; }
    else             { pre = 1.f;       pim = 0.f; }

    Mout[(size_t)b * d * d + i * d + j] = make_float2(routing * pre, routing * pim);
}

// ---------------- generic mix (known-good round-1 version) ----------------
__global__ __launch_bounds__(256)
void mix_kernel(const float* __restrict__ srcR, const float* __restrict__ srcI,
                const float2* __restrict__ M,
                float* __restrict__ dstR, float* __restrict__ dstI,
                int d, int SI, int KL2, int SKL, int SKH)
{
    const int kb0 = blockIdx.x << 6;
    const int it  = blockIdx.y << 6;
    const int b   = blockIdx.z;
    const int msk = (1 << KL2) - 1;

    __shared__ float2 Ms[KT][66];
    __shared__ float2 Us[KT][66];

    const int t  = threadIdx.x;
    const int ti = t & 15, tj = t >> 4;

    float accr[4][4] = {{0}}, acci[4][4] = {{0}};

    const size_t boff = (size_t)b * SSIZE;
    const float2* Mb  = M + (size_t)b * d * d;
    const size_t koff = (size_t)(kb0 >> KL2) * SKH + (size_t)(kb0 & msk) * SKL;

    for (int jb = 0; jb < d; jb += KT) {
        #pragma unroll
        for (int iter = 0; iter < 4; iter++) {
            int l  = iter * 256 + t;
            int jj = l & 15;
            int ii = l >> 4;
            Ms[jj][ii] = Mb[(size_t)(it + ii) * d + (jb + jj)];
        }
        #pragma unroll
        for (int iter = 0; iter < 4; iter++) {
            int l  = iter * 256 + t;
            int kk = l & 63;
            int jj = l >> 6;
            size_t off = boff + (size_t)(jb + jj) * SI + koff + (size_t)kk * SKL;
            Us[jj][kk] = make_float2(srcR[off], srcI[off]);
        }
        __syncthreads();
        #pragma unroll
        for (int jj = 0; jj < KT; jj++) {
            float2 m[4], u[4];
            #pragma unroll
            for (int r = 0; r < 4; r++) m[r] = Ms[jj][ti * 4 + r];
            #pragma unroll
            for (int c = 0; c < 4; c++) u[c] = Us[jj][tj * 4 + c];
            #pragma unroll
            for (int r = 0; r < 4; r++)
                #pragma unroll
                for (int c = 0; c < 4; c++) {
                    accr[r][c] = fmaf(m[r].x,  u[c].x, accr[r][c]);
                    accr[r][c] = fmaf(-m[r].y, u[c].y, accr[r][c]);
                    acci[r][c] = fmaf(m[r].x,  u[c].y, acci[r][c]);
                    acci[r][c] = fmaf(m[r].y,  u[c].x, acci[r][c]);
                }
        }
        __syncthreads();
    }

    #pragma unroll
    for (int r = 0; r < 4; r++)
        #pragma unroll
        for (int c = 0; c < 4; c++) {
            int i = it + ti * 4 + r;
            int kc = tj * 4 + c;
            size_t pos = boff + (size_t)i * SI + koff + (size_t)kc * SKL;
            dstR[pos] = accr[r][c];
            dstI[pos] = acci[r][c];
        }
}

extern "C" void kernel_launch(void* const* d_in, const int* in_sizes, int n_in,
                              void* d_out, int out_size, void* d_ws, size_t ws_size,
                              hipStream_t stream)
{
    const float* xr  = (const float*)d_in[0];
    const float* xi  = (const float*)d_in[1];
    const float* w0r = (const float*)d_in[2];
    const float* w0i = (const float*)d_in[3];
    const float* w1r = (const float*)d_in[4];
    const float* w1i = (const float*)d_in[5];
    const float* w2r = (const float*)d_in[6];
    const float* w2i = (const float*)d_in[7];
    const float* lt  = (const float*)d_in[8];

    float* outR = (float*)d_out;
    float* outI = outR + (size_t)BATCH * SSIZE;

    float*  wsR = (float*)d_ws;
    float*  wsI = wsR + (size_t)BATCH * SSIZE;
    float*  Gf  = wsI + (size_t)BATCH * SSIZE;
    float2* Mf  = (float2*)(Gf + (size_t)BATCH * 128 * 128 * 2);

    const int nG = BATCH * 128 * 128 * 2;

    // ---------------- mode 0: d=128, SI=8192, KL2=13
    zero_kernel<<<dim3((nG + 255) / 256), 256, 0, stream>>>(Gf, nG);
    gram_v4_kernel<8192, 13, 0><<<dim3(4, BATCH, 64), 256, 0, stream>>>(xr, xi, Gf, 128);
    score_kernel<<<dim3(128, BATCH), 128, 0, stream>>>(Gf, w0r, w0i, lt, Mf, 128);
    mix_kernel<<<dim3(128, 2, BATCH), 256, 0, stream>>>(xr, xi, Mf, outR, outI,
                 128, 8192, 13, 1, 0);

    // ---------------- mode 1: d=128, SI=64, KL2=6, SKH=8192
    zero_kernel<<<dim3((nG + 255) / 256), 256, 0, stream>>>(Gf, nG);
    gram_v4_kernel<64, 6, 8192><<<dim3(4, BATCH, 64), 256, 0, stream>>>(outR, outI, Gf, 128);
    score_kernel<<<dim3(128, BATCH), 128, 0, stream>>>(Gf, w1r, w1i, lt, Mf, 128);
    mix_kernel<<<dim3(128, 2, BATCH), 256, 0, stream>>>(outR, outI, Mf, wsR, wsI,
                 128, 64, 6, 1, 8192);

    // ---------------- mode 2: d=64, SI=1, k: (k&127)*64 + (k>>7)*8192
    zero_kernel<<<dim3((nG + 255) / 256), 256, 0, stream>>>(Gf, nG);
    gram64_kernel<<<dim3(BATCH, 64), 256, 0, stream>>>(wsR, wsI, Gf, 256);
    score_kernel<<<dim3(64, BATCH), 64, 0, stream>>>(Gf, w2r, w2i, lt, Mf, 64);
    mix_kernel<<<dim3(256, 1, BATCH), 256, 0, stream>>>(wsR, wsI, Mf, outR, outI,
                 64, 1, 7, 64, 8192);
}

// Round 5
// 1157.912 us; speedup vs baseline: 5.8252x; 1.4141x over previous
//
#include <hip/hip_runtime.h>
#include <math.h>

#define BATCH 8
#define SSIZE 1048576   // 128*128*64
#define KT 16

// ---------------- zero kernel (graph-capture-safe G clear) ----------------
__global__ void zero_kernel(float* __restrict__ p, int n) {
    int i = blockIdx.x * blockDim.x + threadIdx.x;
    if (i < n) p[i] = 0.0f;
}

// =====================================================================
// gram_v4 (modes 0/1, k-contiguous): 64x64 G-tile per block, 4x4 complex
// per thread (32 acc VGPRs -> no spill), single-buffer LDS, float4 global
// staging, conflict-free float4 fragment reads. Bare launch_bounds(256):
// occupancy does the latency hiding. (Round-4 verified fast.)
// u(b,i,k): off = b*SSIZE + i*SI + (k>>KL2)*SKH + (k & ((1<<KL2)-1))
// =====================================================================
template<int SI_, int KL2_, int SKH_>
__global__ __launch_bounds__(256)
void gram_v4_kernel(const float* __restrict__ srcR, const float* __restrict__ srcI,
                    float* __restrict__ G, int kPerBlock)
{
    const int it = (blockIdx.x >> 1) << 6;   // 2x2 tiles of 64 (d=128)
    const int jt = (blockIdx.x & 1) << 6;
    const int b  = blockIdx.y;
    const int kbase0 = blockIdx.z * kPerBlock;

    const int t  = threadIdx.x;
    const int ti = t & 15, tj = t >> 4;

    __shared__ float2 As[KT][66];   // [kk][row]; row pitch 528B (16B-aligned)
    __shared__ float2 Bs[KT][66];

    float accr[4][4] = {{0.f}}, acci[4][4] = {{0.f}};

    const size_t boff = (size_t)b * SSIZE;
    const int nT = kPerBlock >> 4;

    // staging map: kq = float4 index in k (0..3), r0 = row (0..63)
    const int kq = t & 3;
    const int r0 = t >> 2;

    #define GADDR(ii, k) (boff + (size_t)(ii) * SI_ + \
        (size_t)((k) >> KL2_) * SKH_ + (size_t)((k) & ((1 << KL2_) - 1)))

    for (int kt = 0; kt < nT; kt++) {
        const int kb = kbase0 + kt * KT;
        const size_t offA = GADDR(it + r0, kb + kq * 4);
        const size_t offB = GADDR(jt + r0, kb + kq * 4);
        const float4 aR = *(const float4*)(srcR + offA);
        const float4 aI = *(const float4*)(srcI + offA);
        const float4 bR = *(const float4*)(srcR + offB);
        const float4 bI = *(const float4*)(srcI + offB);

        As[kq * 4 + 0][r0] = make_float2(aR.x, aI.x);
        As[kq * 4 + 1][r0] = make_float2(aR.y, aI.y);
        As[kq * 4 + 2][r0] = make_float2(aR.z, aI.z);
        As[kq * 4 + 3][r0] = make_float2(aR.w, aI.w);
        Bs[kq * 4 + 0][r0] = make_float2(bR.x, bI.x);
        Bs[kq * 4 + 1][r0] = make_float2(bR.y, bI.y);
        Bs[kq * 4 + 2][r0] = make_float2(bR.z, bI.z);
        Bs[kq * 4 + 3][r0] = make_float2(bR.w, bI.w);
        __syncthreads();

        #pragma unroll
        for (int kk = 0; kk < KT; kk++) {
            float4 a4[2], b4[2];
            #pragma unroll
            for (int q = 0; q < 2; q++) a4[q] = *(const float4*)&As[kk][2 * ti + 32 * q];
            #pragma unroll
            for (int q = 0; q < 2; q++) b4[q] = *(const float4*)&Bs[kk][2 * tj + 32 * q];
            #pragma unroll
            for (int r = 0; r < 4; r++) {
                const float ax = (r & 1) ? a4[r >> 1].z : a4[r >> 1].x;
                const float ay = (r & 1) ? a4[r >> 1].w : a4[r >> 1].y;
                #pragma unroll
                for (int c = 0; c < 4; c++) {
                    const float bx = (c & 1) ? b4[c >> 1].z : b4[c >> 1].x;
                    const float by = (c & 1) ? b4[c >> 1].w : b4[c >> 1].y;
                    accr[r][c] = fmaf(ax,  bx, accr[r][c]);
                    accr[r][c] = fmaf(-ay, by, accr[r][c]);
                    acci[r][c] = fmaf(ax,  by, acci[r][c]);
                    acci[r][c] = fmaf(ay,  bx, acci[r][c]);
                }
            }
        }
        __syncthreads();
    }
    #undef GADDR

    float* Gb = G + (size_t)b * 128 * 128 * 2;
    #pragma unroll
    for (int r = 0; r < 4; r++) {
        const int i = it + 2 * ti + (r & 1) + 32 * (r >> 1);
        #pragma unroll
        for (int c = 0; c < 4; c++) {
            const int j = jt + 2 * tj + (c & 1) + 32 * (c >> 1);
            atomicAdd(&Gb[(i * 128 + j) * 2 + 0], accr[r][c]);
            atomicAdd(&Gb[(i * 128 + j) * 2 + 1], acci[r][c]);
        }
    }
}

// =====================================================================
// gram64 (mode 2, d=64): SI=1 (i contiguous), k: (k&127)*64 + (k>>7)*8192.
// REWRITTEN in gram_v4 style: bare launch_bounds(256), single-buffer LDS,
// no register prefetch (the old (256,2)-capped dbuf version spilled:
// VGPR=128, 1.4 GB scratch writes, 590 us).
// =====================================================================
__global__ __launch_bounds__(256)
void gram64_kernel(const float* __restrict__ srcR, const float* __restrict__ srcI,
                   float* __restrict__ G, int kPerBlock)
{
    const int b      = blockIdx.x;
    const int kbase0 = blockIdx.y * kPerBlock;
    const int t  = threadIdx.x;
    const int ti = t & 15, tj = t >> 4;

    __shared__ float2 As[32][66];   // [kk][i]; row pitch 528B

    float accr[4][4] = {{0.f}}, acci[4][4] = {{0.f}};

    const size_t boff = (size_t)b * SSIZE;
    const int nT = kPerBlock >> 5;

    // staging map: 16 i-float4 groups x 16 kk, two passes of 16 kk
    const int ii4 = (t & 15) * 4;
    const int kk0 = t >> 4;

    #define GADDR64(ii, k) (boff + (size_t)(ii) + \
        (size_t)((k) & 127) * 64 + (size_t)((k) >> 7) * 8192)

    for (int kt = 0; kt < nT; kt++) {
        const int kb = kbase0 + kt * 32;
        #pragma unroll
        for (int m = 0; m < 2; m++) {
            const int kk = kk0 + 16 * m;
            const size_t off = GADDR64(ii4, kb + kk);
            const float4 pR = *(const float4*)(srcR + off);
            const float4 pI = *(const float4*)(srcI + off);
            *(float4*)&As[kk][ii4]     = make_float4(pR.x, pI.x, pR.y, pI.y);
            *(float4*)&As[kk][ii4 + 2] = make_float4(pR.z, pI.z, pR.w, pI.w);
        }
        __syncthreads();

        #pragma unroll
        for (int kk = 0; kk < 32; kk++) {
            float4 a4[2], b4[2];
            #pragma unroll
            for (int q = 0; q < 2; q++) a4[q] = *(const float4*)&As[kk][2 * ti + 32 * q];
            #pragma unroll
            for (int q = 0; q < 2; q++) b4[q] = *(const float4*)&As[kk][2 * tj + 32 * q];
            #pragma unroll
            for (int r = 0; r < 4; r++) {
                const float ax = (r & 1) ? a4[r >> 1].z : a4[r >> 1].x;
                const float ay = (r & 1) ? a4[r >> 1].w : a4[r >> 1].y;
                #pragma unroll
                for (int c = 0; c < 4; c++) {
                    const float bx = (c & 1) ? b4[c >> 1].z : b4[c >> 1].x;
                    const float by = (c & 1) ? b4[c >> 1].w : b4[c >> 1].y;
                    accr[r][c] = fmaf(ax,  bx, accr[r][c]);
                    accr[r][c] = fmaf(-ay, by, accr[r][c]);
                    acci[r][c] = fmaf(ax,  by, acci[r][c]);
                    acci[r][c] = fmaf(ay,  bx, acci[r][c]);
                }
            }
        }
        __syncthreads();
    }
    #undef GADDR64

    float* Gb = G + (size_t)b * 64 * 64 * 2;
    #pragma unroll
    for (int r = 0; r < 4; r++) {
        const int i = 2 * ti + (r & 1) + 32 * (r >> 1);
        #pragma unroll
        for (int c = 0; c < 4; c++) {
            const int j = 2 * tj + (c & 1) + 32 * (c >> 1);
            atomicAdd(&Gb[(i * 64 + j) * 2 + 0], accr[r][c]);
            atomicAdd(&Gb[(i * 64 + j) * 2 + 1], acci[r][c]);
        }
    }
}

// ---------------- score/softmax/phase -> routing matrix M ----------------
__global__ __launch_bounds__(128)
void score_kernel(const float* __restrict__ G,
                  const float* __restrict__ Wre, const float* __restrict__ Wim,
                  const float* __restrict__ log_tau,
                  float2* __restrict__ Mout, int d)
{
    const int b = blockIdx.y;
    const int i = blockIdx.x;
    const int j = threadIdx.x;

    const float2* Gb = (const float2*)G + (size_t)b * d * d;

    float sre = 0.f, sim = 0.f;
    for (int l = 0; l < d; l++) {
        float wr = Wre[i * d + l];
        float wi = Wim[i * d + l];
        float2 g = Gb[l * d + j];
        sre = fmaf(wr, g.x, sre);
        sre = fmaf(-wi, g.y, sre);
        sim = fmaf(wr, g.y, sim);
        sim = fmaf(wi, g.x, sim);
    }

    float mag = sqrtf(sre * sre + sim * sim);
    float tau = fmaxf(expf(log_tau[0]), 1e-8f);
    float scale = tau * sqrtf((float)SSIZE / (float)d);
    float mval = mag / scale;

    __shared__ float red[128];
    red[j] = mval;
    __syncthreads();
    for (int s = d >> 1; s > 0; s >>= 1) {
        if (j < s) red[j] = fmaxf(red[j], red[j + s]);
        __syncthreads();
    }
    float mx = red[0];
    __syncthreads();
    float e = expf(mval - mx);
    red[j] = e;
    __syncthreads();
    for (int s = d >> 1; s > 0; s >>= 1) {
        if (j < s) red[j] += red[j + s];
        __syncthreads();
    }
    float routing = e / red[0];

    float safe = fmaxf(mag, 1e-8f);
    float pre, pim;
    if (mag > 1e-8f) { pre = sre / safe; pim = sim / safe; }
    else             { pre = 1.f;       pim = 0.f; }

    Mout[(size_t)b * d * d + i * d + j] = make_float2(routing * pre, routing * pim);
}

// ---------------- generic mix (known-good round-1 version) ----------------
__global__ __launch_bounds__(256)
void mix_kernel(const float* __restrict__ srcR, const float* __restrict__ srcI,
                const float2* __restrict__ M,
                float* __restrict__ dstR, float* __restrict__ dstI,
                int d, int SI, int KL2, int SKL, int SKH)
{
    const int kb0 = blockIdx.x << 6;
    const int it  = blockIdx.y << 6;
    const int b   = blockIdx.z;
    const int msk = (1 << KL2) - 1;

    __shared__ float2 Ms[KT][66];
    __shared__ float2 Us[KT][66];

    const int t  = threadIdx.x;
    const int ti = t & 15, tj = t >> 4;

    float accr[4][4] = {{0}}, acci[4][4] = {{0}};

    const size_t boff = (size_t)b * SSIZE;
    const float2* Mb  = M + (size_t)b * d * d;
    const size_t koff = (size_t)(kb0 >> KL2) * SKH + (size_t)(kb0 & msk) * SKL;

    for (int jb = 0; jb < d; jb += KT) {
        #pragma unroll
        for (int iter = 0; iter < 4; iter++) {
            int l  = iter * 256 + t;
            int jj = l & 15;
            int ii = l >> 4;
            Ms[jj][ii] = Mb[(size_t)(it + ii) * d + (jb + jj)];
        }
        #pragma unroll
        for (int iter = 0; iter < 4; iter++) {
            int l  = iter * 256 + t;
            int kk = l & 63;
            int jj = l >> 6;
            size_t off = boff + (size_t)(jb + jj) * SI + koff + (size_t)kk * SKL;
            Us[jj][kk] = make_float2(srcR[off], srcI[off]);
        }
        __syncthreads();
        #pragma unroll
        for (int jj = 0; jj < KT; jj++) {
            float2 m[4], u[4];
            #pragma unroll
            for (int r = 0; r < 4; r++) m[r] = Ms[jj][ti * 4 + r];
            #pragma unroll
            for (int c = 0; c < 4; c++) u[c] = Us[jj][tj * 4 + c];
            #pragma unroll
            for (int r = 0; r < 4; r++)
                #pragma unroll
                for (int c = 0; c < 4; c++) {
                    accr[r][c] = fmaf(m[r].x,  u[c].x, accr[r][c]);
                    accr[r][c] = fmaf(-m[r].y, u[c].y, accr[r][c]);
                    acci[r][c] = fmaf(m[r].x,  u[c].y, acci[r][c]);
                    acci[r][c] = fmaf(m[r].y,  u[c].x, acci[r][c]);
                }
        }
        __syncthreads();
    }

    #pragma unroll
    for (int r = 0; r < 4; r++)
        #pragma unroll
        for (int c = 0; c < 4; c++) {
            int i = it + ti * 4 + r;
            int kc = tj * 4 + c;
            size_t pos = boff + (size_t)i * SI + koff + (size_t)kc * SKL;
            dstR[pos] = accr[r][c];
            dstI[pos] = acci[r][c];
        }
}

extern "C" void kernel_launch(void* const* d_in, const int* in_sizes, int n_in,
                              void* d_out, int out_size, void* d_ws, size_t ws_size,
                              hipStream_t stream)
{
    const float* xr  = (const float*)d_in[0];
    const float* xi  = (const float*)d_in[1];
    const float* w0r = (const float*)d_in[2];
    const float* w0i = (const float*)d_in[3];
    const float* w1r = (const float*)d_in[4];
    const float* w1i = (const float*)d_in[5];
    const float* w2r = (const float*)d_in[6];
    const float* w2i = (const float*)d_in[7];
    const float* lt  = (const float*)d_in[8];

    float* outR = (float*)d_out;
    float* outI = outR + (size_t)BATCH * SSIZE;

    float*  wsR = (float*)d_ws;
    float*  wsI = wsR + (size_t)BATCH * SSIZE;
    float*  Gf  = wsI + (size_t)BATCH * SSIZE;
    float2* Mf  = (float2*)(Gf + (size_t)BATCH * 128 * 128 * 2);

    const int nG = BATCH * 128 * 128 * 2;

    // ---------------- mode 0: d=128, SI=8192, KL2=13
    zero_kernel<<<dim3((nG + 255) / 256), 256, 0, stream>>>(Gf, nG);
    gram_v4_kernel<8192, 13, 0><<<dim3(4, BATCH, 64), 256, 0, stream>>>(xr, xi, Gf, 128);
    score_kernel<<<dim3(128, BATCH), 128, 0, stream>>>(Gf, w0r, w0i, lt, Mf, 128);
    mix_kernel<<<dim3(128, 2, BATCH), 256, 0, stream>>>(xr, xi, Mf, outR, outI,
                 128, 8192, 13, 1, 0);

    // ---------------- mode 1: d=128, SI=64, KL2=6, SKH=8192
    zero_kernel<<<dim3((nG + 255) / 256), 256, 0, stream>>>(Gf, nG);
    gram_v4_kernel<64, 6, 8192><<<dim3(4, BATCH, 64), 256, 0, stream>>>(outR, outI, Gf, 128);
    score_kernel<<<dim3(128, BATCH), 128, 0, stream>>>(Gf, w1r, w1i, lt, Mf, 128);
    mix_kernel<<<dim3(128, 2, BATCH), 256, 0, stream>>>(outR, outI, Mf, wsR, wsI,
                 128, 64, 6, 1, 8192);

    // ---------------- mode 2: d=64, SI=1, k: (k&127)*64 + (k>>7)*8192
    zero_kernel<<<dim3((nG + 255) / 256), 256, 0, stream>>>(Gf, nG);
    gram64_kernel<<<dim3(BATCH, 64), 256, 0, stream>>>(wsR, wsI, Gf, 256);
    score_kernel<<<dim3(64, BATCH), 64, 0, stream>>>(Gf, w2r, w2i, lt, Mf, 64);
    mix_kernel<<<dim3(256, 1, BATCH), 256, 0, stream>>>(wsR, wsI, Mf, outR, outI,
                 64, 1, 7, 64, 8192);
}